// Round 12
// baseline (348.554 us; speedup 1.0000x reference)
//
#include <hip/hip_runtime.h>
#include <stdint.h>

#define TOKENS 8192
#define IN_F   4096
#define OUT_F  4096

#define BM 256
#define BN 256
#define BK 64                 // bytes of K per slice (64 int8)
#define NK (IN_F / BK)        // 64 slices
#define THREADS 1024
#define SLOT 16384            // A-only slot: 256 rows x 64 B

typedef int v4i __attribute__((ext_vector_type(4)));

#define GLOBAL_AS __attribute__((address_space(1)))
#define LDS_AS    __attribute__((address_space(3)))

// ---- fused pack: x int32->int8, W int32 [K][N] -> int8 WT [N][K] ----
#define XBLOCKS (TOKENS * IN_F / 4 / 256)   // 8192
__global__ __launch_bounds__(256) void pack_kernel(const int* __restrict__ x32,
                                                   uint8_t* __restrict__ x8,
                                                   const int* __restrict__ w32,
                                                   uint8_t* __restrict__ wt8) {
  if (blockIdx.x < XBLOCKS) {
    int t = blockIdx.x * 256 + threadIdx.x;
    const int4 v = ((const int4*)x32)[t];
    uint32_t p = (uint32_t)(v.x & 0xFF)
               | ((uint32_t)(v.y & 0xFF) << 8)
               | ((uint32_t)(v.z & 0xFF) << 16)
               | ((uint32_t)(v.w & 0xFF) << 24);
    ((uint32_t*)x8)[t] = p;
  } else {
    int b = blockIdx.x - XBLOCKS;
    int tn = (b & 63) * 64;
    int tk = (b >> 6) * 64;
    int t = threadIdx.x;
    int n  = tn + (t >> 2);
    int k0 = tk + (t & 3) * 16;
    uint32_t words[4];
#pragma unroll
    for (int w = 0; w < 4; ++w) {
      uint32_t acc = 0;
#pragma unroll
      for (int j = 0; j < 4; ++j) {
        int val = w32[(size_t)(k0 + w * 4 + j) * OUT_F + n];
        acc |= (uint32_t)(val & 0xFF) << (8 * j);
      }
      words[w] = acc;
    }
    uint4 o = make_uint4(words[0], words[1], words[2], words[3]);
    *(uint4*)(wt8 + (size_t)n * IN_F + k0) = o;
  }
}

// ---- int8 GEMM: 256x256, 16 waves, A-only LDS ring-4, B direct->regs ----
// B frags loaded one slice ahead into double-buffered regs (16-line gather,
// L1-served). LDS traffic halves vs R9 (A staging+reads only). FIFO audit:
// iter i issues B(i+1)x4 + stageA(i+3); auto-wait before MFMA(i) completes
// B(i) [issued iter i-1] which drains stageA(i+1) [iter i-2, strictly older]
// -> slot (i+1) ready before iter i+1's ds_reads; tail barrier publishes.
// Explicit tail vmcnt(5) drains one extra old stage; never 0 mid-loop.
__global__ __launch_bounds__(THREADS, 4) void gemm_i8_kernel(const uint8_t* __restrict__ A,
                                                             const uint8_t* __restrict__ BT,
                                                             const int* __restrict__ bias,
                                                             const float* __restrict__ scales,
                                                             int* __restrict__ out) {
  __shared__ __align__(16) uint8_t lds[4 * SLOT];   // 64 KiB, A ring of 4 slices

  const int t    = threadIdx.x;
  const int lane = t & 63;
  const int w    = t >> 6;     // 0..15
  const int wm   = w >> 2;     // 0..3
  const int wn   = w & 3;      // 0..3
  const int fr   = lane & 15;
  const int fq   = lane >> 4;

  // XCD-aware bijective swizzle: 512 blocks, 512 % 8 == 0
  int bid = blockIdx.x;
  int swz = (bid & 7) * 64 + (bid >> 3);
  int bm = swz >> 4;           // 0..31
  int bn = swz & 15;           // 0..15

  // A staging: pre-swizzled global source, linear LDS dest (rule #21).
  // sigma(l)=l^((l>>3)&7) on 16B chunks within each 8-KiB half (0-conflict R3-R11).
  const int half = t >> 9;
  const int tt   = t & 511;
  const int lsz  = tt ^ ((tt >> 3) & 7);
  const int srow = half * 128 + (lsz >> 2);   // 0..255
  const int scol = (lsz & 3) * 16;
  const size_t gA = (size_t)(bm * BM + srow) * IN_F + scol;
  const int ldst = half * 8192 + tt * 16;

  auto stageA = [&](int j) {   // ONE load per thread per slice (1 vmcnt item)
    __builtin_amdgcn_global_load_lds((const GLOBAL_AS void*)(A + gA + j * BK),
                                     (LDS_AS void*)(lds + (j & 3) * SLOT + ldst),
                                     16, 0, 0);
  };

  // A frag base offset, sigma-swizzled; m-delta folds into ds_read offset imm
  // (swizzle term ((rl>>1)&7) is m-invariant since m*8 == 0 mod 8).
  const int row0 = wm * 64 + fr;
  const int hh = row0 >> 7, rl = row0 & 127;
  int ab = hh * 8192 + rl * 64 + fq * 16;
  ab ^= ((rl >> 1) & 7) << 4;

  // B per-lane global base: lane (fr,fq) holds BT[col=...+fr][k=fq*16..+16]
  const uint8_t* gB = BT + (size_t)(bn * BN + wn * 64 + fr) * IN_F + fq * 16;

#define LOADB(j, dst)                                                           \
  _Pragma("unroll") for (int n = 0; n < 4; ++n)                                 \
    dst[n] = *(const v4i*)(gB + (size_t)n * (16 * IN_F) + (size_t)(j) * BK);

  v4i acc[4][4];
  const v4i vzero = {0, 0, 0, 0};
#pragma unroll
  for (int m = 0; m < 4; ++m)
#pragma unroll
    for (int n = 0; n < 4; ++n) acc[m][n] = vzero;

  v4i bC[4], bN_[4];

  // Prologue: B(0)->bC, stage A slots 0..2; vmcnt(2) drains (at least) A(0);
  // barrier publishes every wave's slot-0 writes (R6 lesson).
  LOADB(0, bC)
  stageA(0); stageA(1); stageA(2);
  asm volatile("s_waitcnt vmcnt(2)" ::: "memory");
  asm volatile("s_barrier" ::: "memory");

#define BODY(i, DOSTAGE, DOB, bCUR, bNXT)                                       \
  {                                                                             \
    if (DOB) { LOADB((i) + 1, bNXT) }                                           \
    if (DOSTAGE) stageA((i) + 3);                                               \
    const uint8_t* sb = lds + ((i) & 3) * SLOT;                                 \
    v4i af[4];                                                                  \
    _Pragma("unroll") for (int m = 0; m < 4; ++m)                               \
      af[m] = *(const v4i*)(sb + ab + m * 1024);                                \
    __builtin_amdgcn_s_setprio(1);                                              \
    _Pragma("unroll") for (int m = 0; m < 4; ++m)                               \
      _Pragma("unroll") for (int n = 0; n < 4; ++n)                             \
        acc[m][n] = __builtin_amdgcn_mfma_i32_16x16x64_i8(af[m], bCUR[n],       \
                                                          acc[m][n], 0, 0, 0);  \
    __builtin_amdgcn_s_setprio(0);                                              \
  }

#define TAIL(VM)                                                                \
  asm volatile("s_waitcnt vmcnt(" #VM ")" ::: "memory");                        \
  asm volatile("s_barrier" ::: "memory");

  BODY(0, true, true, bC, bN_) TAIL(6)
  for (int i = 1; i < 60; i += 2) {
    BODY(i,     true, true, bN_, bC) TAIL(5)
    BODY(i + 1, true, true, bC, bN_) TAIL(5)
  }
  BODY(61, false, true, bN_, bC) TAIL(4)     // drains A(63) explicitly
  BODY(62, false, true, bC, bN_)
  asm volatile("s_barrier" ::: "memory");
  BODY(63, false, false, bN_, bC)
#undef BODY
#undef TAIL
#undef LOADB

  // ---- epilogue: (acc + bias) * scale * 20, clip, trunc; int32 out ----
  // C/D layout (16x16): col = lane&15, row = (lane>>4)*4 + r
#pragma unroll
  for (int n = 0; n < 4; ++n) {
    const int gn  = bn * BN + wn * 64 + n * 16 + fr;
    const int bsv = bias[gn];
    const float sc = scales[gn] * 20.0f;
#pragma unroll
    for (int m = 0; m < 4; ++m) {
      const int gm0 = bm * BM + wm * 64 + m * 16 + fq * 4;
#pragma unroll
      for (int r = 0; r < 4; ++r) {
        float g = (float)(acc[m][n][r] + bsv) * sc;
        g = fminf(fmaxf(g, -128.0f), 127.0f);
        out[(size_t)(gm0 + r) * OUT_F + gn] = (int)g;
      }
    }
  }
}

extern "C" void kernel_launch(void* const* d_in, const int* in_sizes, int n_in,
                              void* d_out, int out_size, void* d_ws, size_t ws_size,
                              hipStream_t stream) {
  const int*   x32    = (const int*)d_in[0];
  const int*   w32    = (const int*)d_in[1];
  const int*   bias   = (const int*)d_in[2];
  const float* scales = (const float*)d_in[3];
  int* out = (int*)d_out;

  uint8_t* x8  = (uint8_t*)d_ws;                              // 32 MB
  uint8_t* wt8 = (uint8_t*)d_ws + (size_t)TOKENS * IN_F;      // 16 MB

  pack_kernel<<<XBLOCKS + (OUT_F / 64) * (IN_F / 64), 256, 0, stream>>>(x32, x8, w32, wt8);
  gemm_i8_kernel<<<(TOKENS / BM) * (OUT_F / BN), THREADS, 0, stream>>>(x8, wt8, bias, scales, out);
}

// Round 13
// 240.584 us; speedup vs baseline: 1.4488x; 1.4488x over previous
//
#include <hip/hip_runtime.h>
#include <stdint.h>

#define TOKENS 8192
#define IN_F   4096
#define OUT_F  4096

#define BM 256
#define BN 256
#define BK 64                 // bytes of K per slice (64 int8)
#define NK (IN_F / BK)        // 64 slices
#define THREADS 1024

typedef int v4i __attribute__((ext_vector_type(4)));

#define GLOBAL_AS __attribute__((address_space(1)))
#define LDS_AS    __attribute__((address_space(3)))

// ---- fused pack: x int32->int8, W int32 [K][N] -> int8 WT [N][K] ----
#define XBLOCKS (TOKENS * IN_F / 4 / 256)   // 8192
__global__ __launch_bounds__(256) void pack_kernel(const int* __restrict__ x32,
                                                   uint8_t* __restrict__ x8,
                                                   const int* __restrict__ w32,
                                                   uint8_t* __restrict__ wt8) {
  if (blockIdx.x < XBLOCKS) {
    int t = blockIdx.x * 256 + threadIdx.x;
    const int4 v = ((const int4*)x32)[t];
    uint32_t p = (uint32_t)(v.x & 0xFF)
               | ((uint32_t)(v.y & 0xFF) << 8)
               | ((uint32_t)(v.z & 0xFF) << 16)
               | ((uint32_t)(v.w & 0xFF) << 24);
    ((uint32_t*)x8)[t] = p;
  } else {
    int b = blockIdx.x - XBLOCKS;
    int tn = (b & 63) * 64;
    int tk = (b >> 6) * 64;
    int t = threadIdx.x;
    int n  = tn + (t >> 2);
    int k0 = tk + (t & 3) * 16;
    uint32_t words[4];
#pragma unroll
    for (int w = 0; w < 4; ++w) {
      uint32_t acc = 0;
#pragma unroll
      for (int j = 0; j < 4; ++j) {
        int val = w32[(size_t)(k0 + w * 4 + j) * OUT_F + n];
        acc |= (uint32_t)(val & 0xFF) << (8 * j);
      }
      words[w] = acc;
    }
    uint4 o = make_uint4(words[0], words[1], words[2], words[3]);
    *(uint4*)(wt8 + (size_t)n * IN_F + k0) = o;
  }
}

// ---- int8 GEMM: 256x256, 16 waves, ring-4, BARRIER-FREE dataflow flags ----
// R9 geometry (best: 147us) with the per-slice s_barrier replaced by LDS
// producer/consumer counters so waves drift out of lockstep and LDS read
// bursts overlap other waves' MFMA bursts.
//   wcnt[s]: waves whose staging of the slice currently in slot s has LANDED
//            (signaled after counted vmcnt at iter start, 1 iter before use).
//   rcnt[s]: waves done READING slot s (release after lgkm drain).
// Spin targets (slice j in slot j&3, lap j>>2, 16 waves):
//   read j   : wcnt[j&3]    >= 16*((j>>2)+1)
//   stage j+3: rcnt[(j+3)&3] >= 16*((j+3)>>2)   (= all reads of slice j-1)
// Drift bound: a wave can stage j+3 only after ALL waves read slice j-1, and
// can read j only after ALL staged j -> leaders <=3 iters ahead -> ring-4 safe.
__global__ __launch_bounds__(THREADS, 4) void gemm_i8_kernel(const uint8_t* __restrict__ A,
                                                             const uint8_t* __restrict__ BT,
                                                             const int* __restrict__ bias,
                                                             const float* __restrict__ scales,
                                                             int* __restrict__ out) {
  __shared__ __align__(16) uint8_t lds[4 * 32768];   // ring of 4 slices, 128 KiB
  __shared__ int flg[8];                              // [0..3]=wcnt, [4..7]=rcnt

  const int t    = threadIdx.x;
  const int lane = t & 63;
  const int w    = t >> 6;     // 0..15
  const int wm   = w >> 2;     // 0..3
  const int wn   = w & 3;      // 0..3
  const int fr   = lane & 15;
  const int fq   = lane >> 4;

  // XCD-aware bijective swizzle: 512 blocks, 512 % 8 == 0
  int bid = blockIdx.x;
  int swz = (bid & 7) * 64 + (bid >> 3);
  int bm = swz >> 4;           // 0..31
  int bn = swz & 15;           // 0..15

  // staging: pre-swizzled global source, linear LDS dest (rule #21).
  // sigma(l)=l^((l>>3)&7) on 16B chunks per 8-KiB half (0-conflict R3-R11).
  const int half = t >> 9;
  const int tt   = t & 511;
  const int lsz  = tt ^ ((tt >> 3) & 7);
  const int srow = half * 128 + (lsz >> 2);   // 0..255
  const int scol = (lsz & 3) * 16;
  const size_t gA = (size_t)(bm * BM + srow) * IN_F + scol;
  const size_t gB = (size_t)(bn * BN + srow) * IN_F + scol;
  const int ldst = half * 8192 + tt * 16;

  auto stage = [&](int j) {            // 2 loads per thread per slice
    uint8_t* sb = lds + (j & 3) * 32768;
    const int k0 = j * BK;
    __builtin_amdgcn_global_load_lds((const GLOBAL_AS void*)(A + gA + k0),
                                     (LDS_AS void*)(sb + ldst),          16, 0, 0);
    __builtin_amdgcn_global_load_lds((const GLOBAL_AS void*)(BT + gB + k0),
                                     (LDS_AS void*)(sb + 16384 + ldst),  16, 0, 0);
  };

  // fragment read offsets (slot-relative), sigma-swizzled to match staging
  int aoff[4], boff[4];
#pragma unroll
  for (int m = 0; m < 4; ++m) {
    int row = wm * 64 + m * 16 + fr;
    int hh = row >> 7, rl = row & 127;
    int b = rl * 64 + fq * 16;
    b ^= ((rl >> 1) & 7) << 4;
    aoff[m] = hh * 8192 + b;
  }
#pragma unroll
  for (int n = 0; n < 4; ++n) {
    int row = wn * 64 + n * 16 + fr;
    int hh = row >> 7, rl = row & 127;
    int b = rl * 64 + fq * 16;
    b ^= ((rl >> 1) & 7) << 4;
    boff[n] = 16384 + hh * 8192 + b;
  }

  v4i acc[4][4];
  const v4i vzero = {0, 0, 0, 0};
#pragma unroll
  for (int m = 0; m < 4; ++m)
#pragma unroll
    for (int n = 0; n < 4; ++n) acc[m][n] = vzero;

#define SIGNAL(idx)                                                             \
  if (lane == 0) __hip_atomic_fetch_add(&flg[idx], 1, __ATOMIC_RELEASE,         \
                                        __HIP_MEMORY_SCOPE_WORKGROUP);
#define SPIN(idx, tgt)                                                          \
  while (__hip_atomic_load(&flg[idx], __ATOMIC_ACQUIRE,                         \
                           __HIP_MEMORY_SCOPE_WORKGROUP) < (tgt)) { }           \
  asm volatile("" ::: "memory");

  // init flags; the ONLY barrier in the kernel
  if (t < 8) flg[t] = 0;
  __syncthreads();

  // Prologue: stage slices 0..2; vmcnt(4) drains own slice-0 loads; signal.
  stage(0); stage(1); stage(2);
  asm volatile("s_waitcnt vmcnt(4)" ::: "memory");
  SIGNAL(0)

  // Main iter j (0..60):
  //  1. vmcnt(2): outstanding {j+1 (2 loads), j+2 (2)} -> drains j+1; signal
  //     wcnt[j+1] ONE ITER before any reader needs it (slack hides stragglers).
  //  2. spin wcnt[j] (usually satisfied: all signaled during their iter j-1)
  //  3. 8x ds_read frags(j); 16 MFMA (compiler-counted lgkm)
  //  4. lgkm0 + release rcnt[j&3]
  //  5. spin rcnt[(j+3)&3] >= all-read(slice j-1); stage(j+3)
  for (int j = 0; j <= 60; ++j) {
    asm volatile("s_waitcnt vmcnt(2)" ::: "memory");
    SIGNAL((j + 1) & 3)
    SPIN(j & 3, ((j >> 2) + 1) * 16)
    const uint8_t* sb = lds + (j & 3) * 32768;
    v4i af[4], bf[4];
#pragma unroll
    for (int m = 0; m < 4; ++m) af[m] = *(const v4i*)(sb + aoff[m]);
#pragma unroll
    for (int n = 0; n < 4; ++n) bf[n] = *(const v4i*)(sb + boff[n]);
    __builtin_amdgcn_s_setprio(1);
#pragma unroll
    for (int m = 0; m < 4; ++m)
#pragma unroll
      for (int n = 0; n < 4; ++n)
        acc[m][n] = __builtin_amdgcn_mfma_i32_16x16x64_i8(af[m], bf[n],
                                                          acc[m][n], 0, 0, 0);
    __builtin_amdgcn_s_setprio(0);
    asm volatile("s_waitcnt lgkmcnt(0)" ::: "memory");
    SIGNAL(4 + (j & 3))
    SPIN(4 + ((j + 3) & 3), ((j + 3) >> 2) * 16)
    stage(j + 3);
  }

  // Tails (no further staging; signals only for remaining slices)
#define TAILIT(j, VM, DOSIG)                                                    \
  {                                                                             \
    if (DOSIG) {                                                                \
      asm volatile("s_waitcnt vmcnt(" #VM ")" ::: "memory");                    \
      SIGNAL(((j) + 1) & 3)                                                     \
    }                                                                           \
    SPIN((j) & 3, (((j) >> 2) + 1) * 16)                                        \
    const uint8_t* sb = lds + ((j) & 3) * 32768;                                \
    v4i af[4], bf[4];                                                           \
    _Pragma("unroll") for (int m = 0; m < 4; ++m)                               \
      af[m] = *(const v4i*)(sb + aoff[m]);                                      \
    _Pragma("unroll") for (int n = 0; n < 4; ++n)                               \
      bf[n] = *(const v4i*)(sb + boff[n]);                                      \
    __builtin_amdgcn_s_setprio(1);                                              \
    _Pragma("unroll") for (int m = 0; m < 4; ++m)                               \
      _Pragma("unroll") for (int n = 0; n < 4; ++n)                             \
        acc[m][n] = __builtin_amdgcn_mfma_i32_16x16x64_i8(af[m], bf[n],         \
                                                          acc[m][n], 0, 0, 0);  \
    __builtin_amdgcn_s_setprio(0);                                              \
  }

  TAILIT(61, 2, true)    // outstanding {62,63}: vmcnt(2) drains 62
  TAILIT(62, 0, true)    // outstanding {63}: vmcnt(0) drains 63
  TAILIT(63, 0, false)
#undef TAILIT
#undef SIGNAL
#undef SPIN

  // ---- epilogue: (acc + bias) * scale * 20, clip, trunc; int32 out ----
  // C/D layout (16x16): col = lane&15, row = (lane>>4)*4 + r
#pragma unroll
  for (int n = 0; n < 4; ++n) {
    const int gn  = bn * BN + wn * 64 + n * 16 + fr;
    const int bsv = bias[gn];
    const float sc = scales[gn] * 20.0f;
#pragma unroll
    for (int m = 0; m < 4; ++m) {
      const int gm0 = bm * BM + wm * 64 + m * 16 + fq * 4;
#pragma unroll
      for (int r = 0; r < 4; ++r) {
        float g = (float)(acc[m][n][r] + bsv) * sc;
        g = fminf(fmaxf(g, -128.0f), 127.0f);
        out[(size_t)(gm0 + r) * OUT_F + gn] = (int)g;
      }
    }
  }
}

extern "C" void kernel_launch(void* const* d_in, const int* in_sizes, int n_in,
                              void* d_out, int out_size, void* d_ws, size_t ws_size,
                              hipStream_t stream) {
  const int*   x32    = (const int*)d_in[0];
  const int*   w32    = (const int*)d_in[1];
  const int*   bias   = (const int*)d_in[2];
  const float* scales = (const float*)d_in[3];
  int* out = (int*)d_out;

  uint8_t* x8  = (uint8_t*)d_ws;                              // 32 MB
  uint8_t* wt8 = (uint8_t*)d_ws + (size_t)TOKENS * IN_F;      // 16 MB

  pack_kernel<<<XBLOCKS + (OUT_F / 64) * (IN_F / 64), 256, 0, stream>>>(x32, x8, w32, wt8);
  gemm_i8_kernel<<<(TOKENS / BM) * (OUT_F / BN), THREADS, 0, stream>>>(x8, wt8, bias, scales, out);
}

// Round 14
// 183.632 us; speedup vs baseline: 1.8981x; 1.3101x over previous
//
#include <hip/hip_runtime.h>
#include <stdint.h>

#define TOKENS 8192
#define IN_F   4096
#define OUT_F  4096

#define BM 256
#define BN 256
#define BK 128                // bytes of K per phase (128 int8)
#define NPH (IN_F / BK)       // 32 phases
#define THREADS 1024
#define SLOT 65536            // A p0,p1 @0,16384; B p0,p1 @32768,49152

typedef int v4i __attribute__((ext_vector_type(4)));

#define GLOBAL_AS __attribute__((address_space(1)))
#define LDS_AS    __attribute__((address_space(3)))

// ---- fused pack: x int32->int8, W int32 [K][N] -> int8 WT [N][K] ----
#define XBLOCKS (TOKENS * IN_F / 4 / 256)   // 8192
__global__ __launch_bounds__(256) void pack_kernel(const int* __restrict__ x32,
                                                   uint8_t* __restrict__ x8,
                                                   const int* __restrict__ w32,
                                                   uint8_t* __restrict__ wt8) {
  if (blockIdx.x < XBLOCKS) {
    int t = blockIdx.x * 256 + threadIdx.x;
    const int4 v = ((const int4*)x32)[t];
    uint32_t p = (uint32_t)(v.x & 0xFF)
               | ((uint32_t)(v.y & 0xFF) << 8)
               | ((uint32_t)(v.z & 0xFF) << 16)
               | ((uint32_t)(v.w & 0xFF) << 24);
    ((uint32_t*)x8)[t] = p;
  } else {
    int b = blockIdx.x - XBLOCKS;
    int tn = (b & 63) * 64;
    int tk = (b >> 6) * 64;
    int t = threadIdx.x;
    int n  = tn + (t >> 2);
    int k0 = tk + (t & 3) * 16;
    uint32_t words[4];
#pragma unroll
    for (int w = 0; w < 4; ++w) {
      uint32_t acc = 0;
#pragma unroll
      for (int j = 0; j < 4; ++j) {
        int val = w32[(size_t)(k0 + w * 4 + j) * OUT_F + n];
        acc |= (uint32_t)(val & 0xFF) << (8 * j);
      }
      words[w] = acc;
    }
    uint4 o = make_uint4(words[0], words[1], words[2], words[3]);
    *(uint4*)(wt8 + (size_t)n * IN_F + k0) = o;
  }
}

// ---- int8 GEMM: 256x256, 16 waves, BK=128 ring-2 (barrier per 128B of K) ----
// R9 structure with the per-slice fixed cost (vmcnt+barrier+convoy ~400cyc)
// amortized over 2x the work. Each 128B K-phase stored as two 64B-column
// panels keeping the verified 0-conflict sigma layout unchanged.
// Hazards: stage(i+1)->slot (i+1)&1 whose readers (phase i-1) drained via
// MFMA data deps before this phase's barrier. vmcnt(0) at head waits on
// stage(i) issued a full ~5000-cyc phase earlier (HBM latency long hidden).
__global__ __launch_bounds__(THREADS, 4) void gemm_i8_kernel(const uint8_t* __restrict__ A,
                                                             const uint8_t* __restrict__ BT,
                                                             const int* __restrict__ bias,
                                                             const float* __restrict__ scales,
                                                             int* __restrict__ out) {
  __shared__ __align__(16) uint8_t lds[2 * SLOT];   // 128 KiB, ring of 2 phases

  const int t    = threadIdx.x;
  const int lane = t & 63;
  const int w    = t >> 6;     // 0..15
  const int wm   = w >> 2;     // 0..3
  const int wn   = w & 3;      // 0..3
  const int fr   = lane & 15;
  const int fq   = lane >> 4;

  // XCD-aware bijective swizzle: 512 blocks, 512 % 8 == 0
  int bid = blockIdx.x;
  int swz = (bid & 7) * 64 + (bid >> 3);
  int bm = swz >> 4;           // 0..31
  int bn = swz & 15;           // 0..15

  // staging: pre-swizzled global source, linear LDS dest (rule #21).
  // sigma(l)=l^((l>>3)&7) on 16B chunks per 8-KiB half (0-conflict R3-R13).
  const int half = t >> 9;
  const int tt   = t & 511;
  const int lsz  = tt ^ ((tt >> 3) & 7);
  const int srow = half * 128 + (lsz >> 2);   // 0..255
  const int scol = (lsz & 3) * 16;
  const size_t gA = (size_t)(bm * BM + srow) * IN_F + scol;
  const size_t gB = (size_t)(bn * BN + srow) * IN_F + scol;
  const int ldst = half * 8192 + tt * 16;     // within a 16 KiB panel

  auto stage = [&](int j) {   // 4 loads/thread: A p0, A p1, B p0, B p1
    uint8_t* sb = lds + (j & 1) * SLOT;
    const size_t k0 = (size_t)j * BK;
    __builtin_amdgcn_global_load_lds((const GLOBAL_AS void*)(A + gA + k0),
                                     (LDS_AS void*)(sb + ldst),          16, 0, 0);
    __builtin_amdgcn_global_load_lds((const GLOBAL_AS void*)(A + gA + k0 + 64),
                                     (LDS_AS void*)(sb + 16384 + ldst),  16, 0, 0);
    __builtin_amdgcn_global_load_lds((const GLOBAL_AS void*)(BT + gB + k0),
                                     (LDS_AS void*)(sb + 32768 + ldst),  16, 0, 0);
    __builtin_amdgcn_global_load_lds((const GLOBAL_AS void*)(BT + gB + k0 + 64),
                                     (LDS_AS void*)(sb + 49152 + ldst),  16, 0, 0);
  };

  // fragment read offsets (panel-relative, 16 KiB panels), sigma-swizzled
  int aoff[4], boff[4];
#pragma unroll
  for (int m = 0; m < 4; ++m) {
    int row = wm * 64 + m * 16 + fr;
    int hh = row >> 7, rl = row & 127;
    int b = rl * 64 + fq * 16;
    b ^= ((rl >> 1) & 7) << 4;
    aoff[m] = hh * 8192 + b;
  }
#pragma unroll
  for (int n = 0; n < 4; ++n) {
    int row = wn * 64 + n * 16 + fr;
    int hh = row >> 7, rl = row & 127;
    int b = rl * 64 + fq * 16;
    b ^= ((rl >> 1) & 7) << 4;
    boff[n] = hh * 8192 + b;
  }

  v4i acc[4][4];
  const v4i vzero = {0, 0, 0, 0};
#pragma unroll
  for (int m = 0; m < 4; ++m)
#pragma unroll
    for (int n = 0; n < 4; ++n) acc[m][n] = vzero;

  // Prologue: stage phase 0 only (depth-1 prefetch).
  stage(0);

  for (int i = 0; i < NPH; ++i) {
    asm volatile("s_waitcnt vmcnt(0)" ::: "memory");   // stage(i) landed (issued 1 phase ago)
    asm volatile("s_barrier" ::: "memory");            // all waves' writes visible
    if (i + 1 < NPH) stage(i + 1);                     // into slot read in phase i-1
    const uint8_t* sb = lds + (i & 1) * SLOT;
    // two 64B k-panels; compiler interleaves reads/MFMAs with counted lgkm
#pragma unroll
    for (int p = 0; p < 2; ++p) {
      v4i af[4], bf[4];
#pragma unroll
      for (int m = 0; m < 4; ++m) af[m] = *(const v4i*)(sb + p * 16384 + aoff[m]);
#pragma unroll
      for (int n = 0; n < 4; ++n) bf[n] = *(const v4i*)(sb + 32768 + p * 16384 + boff[n]);
      __builtin_amdgcn_s_setprio(1);
#pragma unroll
      for (int m = 0; m < 4; ++m)
#pragma unroll
        for (int n = 0; n < 4; ++n)
          acc[m][n] = __builtin_amdgcn_mfma_i32_16x16x64_i8(af[m], bf[n],
                                                            acc[m][n], 0, 0, 0);
      __builtin_amdgcn_s_setprio(0);
    }
  }

  // ---- epilogue: (acc + bias) * scale * 20, clip, trunc; int32 out ----
  // C/D layout (16x16): col = lane&15, row = (lane>>4)*4 + r
#pragma unroll
  for (int n = 0; n < 4; ++n) {
    const int gn  = bn * BN + wn * 64 + n * 16 + fr;
    const int bsv = bias[gn];
    const float sc = scales[gn] * 20.0f;
#pragma unroll
    for (int m = 0; m < 4; ++m) {
      const int gm0 = bm * BM + wm * 64 + m * 16 + fq * 4;
#pragma unroll
      for (int r = 0; r < 4; ++r) {
        float g = (float)(acc[m][n][r] + bsv) * sc;
        g = fminf(fmaxf(g, -128.0f), 127.0f);
        out[(size_t)(gm0 + r) * OUT_F + gn] = (int)g;
      }
    }
  }
}

extern "C" void kernel_launch(void* const* d_in, const int* in_sizes, int n_in,
                              void* d_out, int out_size, void* d_ws, size_t ws_size,
                              hipStream_t stream) {
  const int*   x32    = (const int*)d_in[0];
  const int*   w32    = (const int*)d_in[1];
  const int*   bias   = (const int*)d_in[2];
  const float* scales = (const float*)d_in[3];
  int* out = (int*)d_out;

  uint8_t* x8  = (uint8_t*)d_ws;                              // 32 MB
  uint8_t* wt8 = (uint8_t*)d_ws + (size_t)TOKENS * IN_F;      // 16 MB

  pack_kernel<<<XBLOCKS + (OUT_F / 64) * (IN_F / 64), 256, 0, stream>>>(x32, x8, w32, wt8);
  gemm_i8_kernel<<<(TOKENS / BM) * (OUT_F / BN), THREADS, 0, stream>>>(x8, wt8, bias, scales, out);
}